// Round 1
// baseline (97.026 us; speedup 1.0000x reference)
//
#include <hip/hip_runtime.h>

// Problem constants (from reference): X[1536,1536] fp32, W[1536,4608] fp32,
// G[1536,12,36] fp32. Output: scalar (sum Y)^2 where
// Y[b,j] = sum_i X[b,i] W[i,j] G[b,i/128,j/128].
// Algebraic collapse: s = sum_{b,i} X[b,i] * dot36(Wsum[i,:], G[b,i/128,:])
// with Wsum[i,jb] = sum of W[i, jb*128 .. jb*128+128).

#define B_DIM 1536
#define DI    1536
#define DO    4608
#define BS    128
#define NI    12   // DI/BS
#define NJ    36   // DO/BS
#define BTILE 16   // batch rows per block in kernel 2

// ---------------- Kernel 1: Wsum[i][jb] = row-block sums of W ----------------
// One 64-lane wave per (i, jb) pair: each lane loads a float2 (512 B/wave,
// coalesced), butterfly-reduce, lane 0 writes. 55296 waves total.
__global__ __launch_bounds__(256) void wsum_kernel(const float* __restrict__ W,
                                                   float* __restrict__ Wsum) {
    int wave = (blockIdx.x * 256 + threadIdx.x) >> 6;   // global wave id = pair id
    int lane = threadIdx.x & 63;
    int i  = wave / NJ;
    int jb = wave % NJ;
    const float2* p = (const float2*)(W + (size_t)i * DO + (size_t)jb * BS);
    float2 v = p[lane];
    float s = v.x + v.y;
    #pragma unroll
    for (int off = 32; off > 0; off >>= 1)
        s += __shfl_down(s, off, 64);
    if (lane == 0) Wsum[wave] = s;
}

// ---------------- Kernel 2: gated reduction over (b, i) ----------------
// Grid: (B/BTILE) * NI blocks of 256 threads. Block handles (ib, 16 b's).
// Wsum[ib-block] (128x36) staged in LDS with stride 37 (conflict-free:
// 37*lane mod 32 = 5*lane mod 32 is a permutation; 2 lanes/bank is free).
__global__ __launch_bounds__(256) void gated_kernel(const float* __restrict__ X,
                                                    const float* __restrict__ G,
                                                    const float* __restrict__ Wsum,
                                                    float* __restrict__ partials) {
    __shared__ float ws[BS * 37];     // 128 x 36, padded stride 37 (~18.9 KB)
    __shared__ float gs[BTILE * NJ];  // 16 x 36 gate rows for this block
    __shared__ float red[4];

    const int ib   = blockIdx.x % NI;
    const int tile = blockIdx.x / NI;
    const int b0   = tile * BTILE;
    const int t    = threadIdx.x;

    // Stage Wsum block (contiguous 4608 floats in global) into padded LDS.
    const float* wbase = Wsum + (size_t)ib * BS * NJ;
    for (int e = t; e < BS * NJ; e += 256) {
        int r = e / NJ, c = e - r * NJ;
        ws[r * 37 + c] = wbase[e];
    }
    // Stage the 16 gate rows (36 floats each) for this (b-tile, ib).
    for (int e = t; e < BTILE * NJ; e += 256) {
        int bb = e / NJ, k = e - bb * NJ;
        gs[e] = G[((size_t)(b0 + bb) * NI + ib) * NJ + k];
    }
    __syncthreads();

    const int wave = t >> 6, lane = t & 63;
    float waveAcc = 0.f;
    for (int bb = wave; bb < BTILE; bb += 4) {
        const int b = b0 + bb;
        const float* xrow = X + (size_t)b * DI + (size_t)ib * BS;
        const float* grow = gs + bb * NJ;   // wave-uniform -> LDS broadcast (free)
        float p = 0.f;
        #pragma unroll
        for (int r = 0; r < 2; ++r) {
            const int il = lane + 64 * r;
            float x = xrow[il];             // 256 B coalesced per wave
            float acc = 0.f;
            #pragma unroll
            for (int k = 0; k < NJ; ++k)
                acc += ws[il * 37 + k] * grow[k];
            p += x * acc;
        }
        #pragma unroll
        for (int off = 32; off > 0; off >>= 1)
            p += __shfl_down(p, off, 64);
        if (lane == 0) waveAcc += p;
    }
    if (lane == 0) red[wave] = waveAcc;
    __syncthreads();
    if (t == 0) partials[blockIdx.x] = red[0] + red[1] + red[2] + red[3];
}

// ---------------- Kernel 3: final reduce + square ----------------
__global__ __launch_bounds__(256) void finish_kernel(const float* __restrict__ partials,
                                                     int n, float* __restrict__ out) {
    __shared__ float red[4];
    const int t = threadIdx.x;
    float s = 0.f;
    for (int e = t; e < n; e += 256) s += partials[e];
    #pragma unroll
    for (int off = 32; off > 0; off >>= 1)
        s += __shfl_down(s, off, 64);
    const int wave = t >> 6, lane = t & 63;
    if (lane == 0) red[wave] = s;
    __syncthreads();
    if (t == 0) {
        float tot = red[0] + red[1] + red[2] + red[3];
        out[0] = tot * tot;
    }
}

extern "C" void kernel_launch(void* const* d_in, const int* in_sizes, int n_in,
                              void* d_out, int out_size, void* d_ws, size_t ws_size,
                              hipStream_t stream) {
    const float* X = (const float*)d_in[0];  // [1536,1536]
    const float* W = (const float*)d_in[1];  // [1536,4608]
    const float* G = (const float*)d_in[2];  // [1536,12,36]
    float* out = (float*)d_out;

    // Workspace layout (floats): [0, 55296) Wsum; [55296, 55296+1152) partials.
    float* Wsum     = (float*)d_ws;
    float* partials = Wsum + (size_t)DI * NJ;
    const int n_partials = (B_DIM / BTILE) * NI;   // 96 * 12 = 1152

    // Kernel 1: 55296 waves = 13824 blocks x 4 waves.
    wsum_kernel<<<(DI * NJ) / 4, 256, 0, stream>>>(W, Wsum);
    // Kernel 2: 1152 blocks.
    gated_kernel<<<n_partials, 256, 0, stream>>>(X, G, Wsum, partials);
    // Kernel 3: single block.
    finish_kernel<<<1, 256, 0, stream>>>(partials, n_partials, out);
}

// Round 2
// 94.671 us; speedup vs baseline: 1.0249x; 1.0249x over previous
//
#include <hip/hip_runtime.h>

// s = sum_{b,i,j} X[b,i] W[i,j] G[b,i/128,j/128]; out = s^2.
// Factor over j:  s = sum_{i,jb} Wsum[i,jb] * H[i,jb],
//   Wsum[i,jb] = sum_{c<128} W[i, jb*128+c]
//   H[i,jb]    = sum_b X[b,i] * G[b, i/128, jb]
// Kernel 1: Wsum (HBM-bound, 28.3 MB). Kernel 2: lane<->i mapping, G rows are
// wave-uniform -> scalar loads; X coalesced; 36 independent FMA accumulators.
// Finish (square) folded into kernel 2 via last-block detection.

#define B_DIM 1536
#define DI    1536
#define DO    4608
#define NI    12
#define NJ    36
#define GROW  (NI * NJ)          // 432 floats per G batch-row
#define K2_WAVES 1152            // 24 i-blocks x 48 b-ranges
#define K2_BLOCKS (K2_WAVES / 4) // 288

// ---- Kernel 1: Wsum[i][jb]; wave handles (i, jb-pair); lane loads float4 ----
__global__ __launch_bounds__(256) void wsum_kernel(const float* __restrict__ W,
                                                   float* __restrict__ Wsum,
                                                   float* __restrict__ acc,
                                                   unsigned* __restrict__ counter) {
    if (blockIdx.x == 0 && threadIdx.x == 0) { *acc = 0.f; *counter = 0u; }
    int g    = blockIdx.x * 4 + (threadIdx.x >> 6);  // global wave id, 27648 total
    int lane = threadIdx.x & 63;
    int i = g / 18;          // row
    int w = g - i * 18;      // jb-pair: covers jb = 2w, 2w+1 (256 floats, 1 KB)
    const float4* p = (const float4*)(W + (size_t)i * DO + (size_t)w * 256);
    float4 v = p[lane];
    float s = (v.x + v.y) + (v.z + v.w);
    // xor-butterfly within each 32-lane half (halves don't mix for off<32)
    #pragma unroll
    for (int off = 16; off > 0; off >>= 1) s += __shfl_xor(s, off, 64);
    if (lane == 0)  Wsum[i * NJ + 2 * w]     = s;
    if (lane == 32) Wsum[i * NJ + 2 * w + 1] = s;
}

// ---- Kernel 2: H-accumulate + dot with Wsum + grid reduction + square ----
__global__ __launch_bounds__(256) void gated_kernel(const float* __restrict__ X,
                                                    const float* __restrict__ G,
                                                    const float* __restrict__ Wsum,
                                                    float* __restrict__ acc,
                                                    unsigned* __restrict__ counter,
                                                    float* __restrict__ out) {
    __shared__ float red[4];
    const int t    = threadIdx.x;
    const int w    = __builtin_amdgcn_readfirstlane(t >> 6);  // provably uniform
    const int lane = t & 63;
    const int wave = blockIdx.x * 4 + w;     // 0..1151
    const int iblk = wave % 24;              // 64-wide i-block
    const int brng = wave / 24;              // 0..47, 32 b's each
    const int b0   = brng * 32;
    const int i    = iblk * 64 + lane;
    const int ib   = iblk >> 1;              // uniform: 64-block within one 128-block

    float acc36[NJ];
    #pragma unroll
    for (int k = 0; k < NJ; ++k) acc36[k] = 0.f;

    const float* xp = X + (size_t)b0 * DI + i;
    const float4* gp = (const float4*)(G + (size_t)b0 * GROW + (size_t)ib * NJ);
    const int gstride4 = GROW / 4;           // 108 float4 per batch-row

    #pragma unroll 8
    for (int bb = 0; bb < 32; ++bb) {
        float x = xp[(size_t)bb * DI];                    // coalesced, lane<->i
        const float4* g4 = gp + (size_t)bb * gstride4;    // wave-uniform -> s_load
        #pragma unroll
        for (int k4 = 0; k4 < 9; ++k4) {
            float4 gv = g4[k4];
            acc36[4*k4+0] = fmaf(x, gv.x, acc36[4*k4+0]);
            acc36[4*k4+1] = fmaf(x, gv.y, acc36[4*k4+1]);
            acc36[4*k4+2] = fmaf(x, gv.z, acc36[4*k4+2]);
            acc36[4*k4+3] = fmaf(x, gv.w, acc36[4*k4+3]);
        }
    }

    // per-lane dot with Wsum row i (L2-resident, 144 B per lane, once per wave)
    float s = 0.f;
    const float4* wsv = (const float4*)(Wsum + (size_t)i * NJ);
    #pragma unroll
    for (int k4 = 0; k4 < 9; ++k4) {
        float4 w4 = wsv[k4];
        s += w4.x * acc36[4*k4] + w4.y * acc36[4*k4+1]
           + w4.z * acc36[4*k4+2] + w4.w * acc36[4*k4+3];
    }
    #pragma unroll
    for (int off = 1; off < 64; off <<= 1) s += __shfl_xor(s, off, 64);
    if (lane == 0) red[w] = s;
    __syncthreads();
    if (t == 0) {
        float bs = (red[0] + red[1]) + (red[2] + red[3]);
        atomicAdd(acc, bs);
        __threadfence();
        unsigned old = atomicAdd(counter, 1u);
        if (old == (unsigned)gridDim.x - 1u) {
            float tot = atomicAdd(acc, 0.0f);  // atomic read: device-coherent
            out[0] = tot * tot;
        }
    }
}

extern "C" void kernel_launch(void* const* d_in, const int* in_sizes, int n_in,
                              void* d_out, int out_size, void* d_ws, size_t ws_size,
                              hipStream_t stream) {
    const float* X = (const float*)d_in[0];  // [1536,1536]
    const float* W = (const float*)d_in[1];  // [1536,4608]
    const float* G = (const float*)d_in[2];  // [1536,12,36]
    float* out = (float*)d_out;

    float*    Wsum    = (float*)d_ws;                       // 55296 floats
    float*    acc     = Wsum + (size_t)DI * NJ;             // 1 float
    unsigned* counter = (unsigned*)(acc + 1);               // 1 uint

    // Kernel 1: 27648 waves = 6912 blocks x 4 waves (also zeroes acc/counter).
    wsum_kernel<<<(DI * 18) / 4, 256, 0, stream>>>(W, Wsum, acc, counter);
    // Kernel 2: 288 blocks x 256 threads; writes out = s^2 from the last block.
    gated_kernel<<<K2_BLOCKS, 256, 0, stream>>>(X, G, Wsum, acc, counter, out);
}